// Round 5
// baseline (263.066 us; speedup 1.0000x reference)
//
#include <hip/hip_runtime.h>
#include <math.h>

#define NCLS 15
constexpr int BB = 8;
constexpr int GG = 60;
constexpr int AA = 21504;   // 128*128 + 64*64 + 32*32
constexpr int TK = 10;
constexpr int GREC = 12;

// ---------- fast math (hw-native, ~1ulp) ----------
__device__ __forceinline__ float frcp_(float x){ return __builtin_amdgcn_rcpf(x); }
__device__ __forceinline__ float flog2_(float x){ return __builtin_amdgcn_logf(x); }
__device__ __forceinline__ float fexp2_(float x){ return __builtin_amdgcn_exp2f(x); }
__device__ __forceinline__ float fsqrt_(float x){ return __builtin_amdgcn_sqrtf(x); }
#define LN2F  0.69314718055994531f
#define RLN2F 1.44269504088896341f
#define R2PIF 0.15915494309189535f
__device__ __forceinline__ float flog_(float x){ return flog2_(x) * LN2F; }
__device__ __forceinline__ float fexp_(float x){ return fexp2_(x * RLN2F); }
__device__ __forceinline__ float fsig_(float x){ return frcp_(1.0f + fexp2_(-x * RLN2F)); }

// ---------- helpers ----------

__device__ __forceinline__ void ageom(int a, float& xc, float& yc, float& rad) {
  if (a < 16384) {
    int i = a >> 7, j = a & 127;
    xc = (j + 0.5f) * 8.0f;  yc = (i + 0.5f) * 8.0f;  rad = 20.0f;
  } else if (a < 20480) {
    int l = a - 16384; int i = l >> 6, j = l & 63;
    xc = (j + 0.5f) * 16.0f; yc = (i + 0.5f) * 16.0f; rad = 40.0f;
  } else {
    int l = a - 20480; int i = l >> 5, j = l & 31;
    xc = (j + 0.5f) * 32.0f; yc = (i + 0.5f) * 32.0f; rad = 80.0f;
  }
}

__device__ __forceinline__ float prob_iou_fast(float x1,float y1,float a1,float b1,float c1,float d1,
                                               float x2,float y2,float a2,float b2,float c2,float d2) {
  float dx = x1 - x2, dy = y1 - y2;
  float Av = a1 + a2, Bv = b1 + b2, Cv = c1 + c2;
  float den = Av*Bv - Cv*Cv + 1e-8f;
  float q = 0.25f*(Av*dy*dy + Bv*dx*dx) - 0.5f*(Cv*dx*dy);
  float t12 = q * frcp_(den);
  float t3 = 0.5f*LN2F*(flog2_(den) - flog2_(4.0f*fsqrt_(d1*d2) + 1e-8f));
  float bd = t12 + t3;
  bd = fminf(fmaxf(bd, 1e-8f), 100.0f);
  float e = 1.0f - fexp2_(-bd * RLN2F);
  e = fminf(fmaxf(e, 0.0f), 1.0f);
  return 1.0f - fsqrt_(e);
}

// static-index insertion (register-resident; rule #20)
__device__ __forceinline__ void ins_cost(float (&cst)[TK], int (&cid)[TK], float c, int id) {
  bool ins = (c < cst[TK-1]) || (c == cst[TK-1] && id < cid[TK-1]);
  if (ins) {
    cst[TK-1] = c; cid[TK-1] = id;
    #pragma unroll
    for (int k = TK-1; k > 0; k--) {
      float tc = cst[k-1]; int ti = cid[k-1];
      bool sw = (cst[k] < tc) || (cst[k] == tc && cid[k] < ti);
      if (sw) { cst[k-1] = cst[k]; cid[k-1] = cid[k]; cst[k] = tc; cid[k] = ti; }
    }
  }
}

__device__ __forceinline__ void ins_vio(float (&vio)[TK], float v) {
  if (v > vio[TK-1]) {
    vio[TK-1] = v;
    #pragma unroll
    for (int k = TK-1; k > 0; k--) {
      float tv = vio[k-1];
      bool sw = vio[k] > tv;
      if (sw) { vio[k-1] = vio[k]; vio[k] = tv; }
    }
  }
}

// ---------- kernels ----------

// one block per (b,g): thread0 builds gt record; all threads rasterize cand cells.
__global__ __launch_bounds__(256) void k_gtraster(const float* __restrict__ labels,
                                                  float* __restrict__ grec, float* acc,
                                                  unsigned char* __restrict__ cand) {
  int bg = blockIdx.x;
  int b = bg / GG;
  __shared__ float sgx, sgy, shw, shh;
  __shared__ int svalid;
  if (threadIdx.x == 0) {
    const float* L = labels + (size_t)bg * 6;
    float ssum = 0.0f;
    for (int k = 0; k < 6; k++) ssum += L[k];
    float valid = (ssum > 0.0f) ? 1.0f : 0.0f;
    float x = L[1], y = L[2], w = L[3], h = L[4], ang = L[5];
    float w2 = w*w/12.0f, h2 = h*h/12.0f;
    float cc = cosf(ang), sn = sinf(ang);
    float cA = w2*cc*cc + h2*sn*sn;
    float cB = w2*sn*sn + h2*cc*cc;
    float cC = (w2-h2)*cc*sn;
    float cD = fmaxf(cA*cB - cC*cC, 0.0f);
    float* gr = grec + (size_t)bg * GREC;
    gr[0]=x; gr[1]=y; gr[2]=cA; gr[3]=cB; gr[4]=cC; gr[5]=cD;
    gr[6]=w; gr[7]=h; gr[8]=__int_as_float((int)L[0]); gr[9]=valid; gr[10]=0.0f; gr[11]=0.0f;
    if (valid != 0.0f) atomicAdd(&acc[4], 1.0f);
    sgx = x; sgy = y; shw = 0.5f*w; shh = 0.5f*h;
    svalid = (valid != 0.0f) ? 1 : 0;
  }
  __syncthreads();
  if (!svalid) return;
  float gx = sgx, gy = sgy, hw = shw, hh = shh;
  unsigned char* cb = cand + (size_t)b * AA;
  int tid = threadIdx.x;
  #pragma unroll
  for (int lvl = 0; lvl < 3; lvl++) {
    const int   W    = (lvl==0)?128:((lvl==1)?64:32);
    const int   base = (lvl==0)?0:((lvl==1)?16384:20480);
    const float s    = (lvl==0)?8.0f:((lvl==1)?16.0f:32.0f);
    const float invs = (lvl==0)?0.125f:((lvl==1)?0.0625f:0.03125f);
    const float rad  = 2.5f*s;
    #pragma unroll
    for (int rc = 0; rc < 2; rc++) {
      float mx = rc ? rad : hw;
      float my = rc ? rad : hh;
      int jlo = (int)floorf((gx - mx)*invs - 0.5f) - 1; if (jlo < 0) jlo = 0;
      int jhi = (int)ceilf ((gx + mx)*invs - 0.5f) + 1; if (jhi > W-1) jhi = W-1;
      int ilo = (int)floorf((gy - my)*invs - 0.5f) - 1; if (ilo < 0) ilo = 0;
      int ihi = (int)ceilf ((gy + my)*invs - 0.5f) + 1; if (ihi > W-1) ihi = W-1;
      if (jhi < jlo || ihi < ilo) continue;
      int nw = jhi - jlo + 1;
      int tot = nw * (ihi - ilo + 1);
      for (int k = tid; k < tot; k += 256) {
        int q = k / nw;
        int ii = ilo + q;
        int jj = jlo + (k - q*nw);
        float dx = fabsf(((float)jj + 0.5f)*s - gx);
        float dy = fabsf(((float)ii + 0.5f)*s - gy);
        if (dx < mx && dy < my) cb[base + ii*W + jj] = 1;
      }
    }
  }
}

// decode + wave-compaction of cand indices.
__global__ __launch_bounds__(256) void k_decode(const float* __restrict__ o8, const float* __restrict__ o16,
                                                const float* __restrict__ o32,
                                                float* __restrict__ rec8, float* __restrict__ Dp,
                                                const unsigned char* __restrict__ cand,
                                                int* ncand, int* __restrict__ clist) {
  int t = blockIdx.x * 256 + threadIdx.x;
  int b = t / AA, a = t - b*AA;

  const float* pb; int cs, i, j; float s;
  if (a < 16384)      { pb = o8  + ((size_t)b*21)*16384 + a;           cs = 16384; i = a>>7; j = a&127; s = 8.0f; }
  else if (a < 20480) { int l = a-16384; pb = o16 + ((size_t)b*21)*4096 + l; cs = 4096;  i = l>>6; j = l&63;  s = 16.0f; }
  else                { int l = a-20480; pb = o32 + ((size_t)b*21)*1024 + l; cs = 1024;  i = l>>5; j = l&31;  s = 32.0f; }

  float tx  = pb[0];
  float ty  = pb[(size_t)cs];
  float tw  = pb[(size_t)2*cs];
  float th  = pb[(size_t)3*cs];
  float ang = pb[(size_t)4*cs];
  float obj = pb[(size_t)5*cs];

  float x = (tx + (float)j) * s;
  float y = (ty + (float)i) * s;
  float w = fexp_(tw) * s;
  float h = fexp_(th) * s;

  float w2 = w*w / 12.0f, h2 = h*h / 12.0f;
  float rev = ang * R2PIF;
  float cc = __builtin_amdgcn_cosf(rev), sn = __builtin_amdgcn_sinf(rev);
  float cA = w2*cc*cc + h2*sn*sn;
  float cB = w2*sn*sn + h2*cc*cc;
  float cC = (w2 - h2)*cc*sn;
  float cD = fmaxf(cA*cB - cC*cC, 0.0f);

  float sobj = fsig_(obj);
  float S = 0.0f;
  float* dpb = Dp + (size_t)b*NCLS*AA + a;
  #pragma unroll
  for (int c = 0; c < NCLS; c++) {
    float xl = pb[(size_t)(6+c)*cs];
    float p  = fsqrt_(fsig_(xl) * sobj);
    p = fminf(fmaxf(p, 1e-7f), 1.0f - 1e-7f);
    float l1 = flog_(1.0f - p);
    float l2 = flog_(p);
    S -= l1;
    dpb[(size_t)c*AA] = l1 - l2;
  }
  float4* r4 = (float4*)(rec8 + (size_t)t * 8);
  r4[0] = make_float4(x, y, cA, cB);
  r4[1] = make_float4(cC, cD, S, obj);

  // wave-aggregated compaction of cand anchors
  int pred = cand[t];
  unsigned long long m = __ballot(pred != 0);
  if (m) {
    int lane = threadIdx.x & 63;
    int base = 0;
    if (lane == 0) base = atomicAdd(&ncand[b], (int)__popcll(m));
    base = __shfl(base, 0);
    if (pred) {
      int off = (int)__popcll(m & ((1ull << lane) - 1ull));
      clist[(size_t)b*AA + base + off] = a;
    }
  }
}

// 2 blocks (8 waves) per (b,g). Per-lane top-10 -> in-register wave merge via
// shuffle argmin rounds -> per-block 4-way serial merge -> part lists.
// Last block folds in the global 2-way merge + dyn_k + match atomics.
__global__ __launch_bounds__(256) void k_assign(const float* __restrict__ rec8, const float* __restrict__ grec,
                                                const float* __restrict__ Dp, const int* __restrict__ ncand,
                                                const int* __restrict__ clist,
                                                float* __restrict__ part_c, int* __restrict__ part_i,
                                                float* __restrict__ part_v,
                                                int* done, int* __restrict__ mcount, int* __restrict__ mgsum) {
  int blk = blockIdx.x;
  int bg = blk >> 1, sp = blk & 1;
  int b = bg / GG;
  int tid = threadIdx.x, wv = tid >> 6, lane = tid & 63;
  const float* gr = grec + (size_t)bg * GREC;

  __shared__ int s_nboth, s_last;
  __shared__ float sh_c[4][TK];
  __shared__ int   sh_i[4][TK];
  __shared__ float sh_v[4][TK];

  if (gr[9] != 0.0f) {
    float gx = gr[0], gy = gr[1], gA = gr[2], gB = gr[3], gC = gr[4], gD = gr[5];
    float hw = 0.5f*gr[6], hh = 0.5f*gr[7];
    int gcls = __float_as_int(gr[8]);
    if (tid == 0) s_nboth = 0;
    __syncthreads();

    float cst[TK]; int cid[TK]; float vio[TK];
    #pragma unroll
    for (int k = 0; k < TK; k++) { cst[k]=3.4e38f; cid[k]=0x7fffffff; vio[k]=-1.0f; }

    const float* recb = rec8 + (size_t)b*AA*8;
    const float* dpp  = Dp + ((size_t)b*NCLS + gcls)*AA;
    const int*   cl   = clist + (size_t)b*AA;
    int n = ncand[b];

    for (int k = (sp*4 + wv)*64 + lane; k < n; k += 512) {
      int a = cl[k];
      const float4* r4 = (const float4*)(recb + (size_t)a*8);
      float4 v0 = r4[0], v1 = r4[1];
      float iou = prob_iou_fast(gx,gy,gA,gB,gC,gD, v0.x,v0.y,v0.z,v0.w,v1.x,v1.y);
      if (iou > vio[TK-1]) ins_vio(vio, iou);
      float xc, yc, rad; ageom(a, xc, yc, rad);
      float dx = fabsf(xc-gx), dy = fabsf(yc-gy);
      bool both = (dx<hw) && (dy<hh) && (dx<rad) && (dy<rad);
      int nb = *((volatile int*)&s_nboth);
      if (both || nb < TK) {   // sound: 10 both-pairs in block => all !both excluded
        float cost = (v1.z + dpp[a]) + 3.0f*(-flog_(iou + 1e-8f));
        if (!both) cost += 1e5f;
        ins_cost(cst, cid, cost, a);
        if (both) atomicAdd(&s_nboth, 1);
      }
    }

    // wave top-10 (cost,id) via 10 rounds of head-argmin butterfly
    float mc = 0.0f, mv = 0.0f; int mi = 0;
    #pragma unroll
    for (int r = 0; r < TK; r++) {
      float c = cst[0]; int i = cid[0];
      #pragma unroll
      for (int o = 1; o < 64; o <<= 1) {
        float oc = __shfl_xor(c, o); int oi = __shfl_xor(i, o);
        bool tk2 = (oc < c) || (oc == c && oi < i);
        c = tk2 ? oc : c; i = tk2 ? oi : i;
      }
      bool win = (cst[0] == c) && (cid[0] == i);
      unsigned long long wm = __ballot(win);
      int wl = (int)__builtin_ctzll(wm);
      if (lane == wl) {
        #pragma unroll
        for (int k = 0; k < TK-1; k++) { cst[k]=cst[k+1]; cid[k]=cid[k+1]; }
        cst[TK-1]=3.4e38f; cid[TK-1]=0x7fffffff;
      }
      if (lane == r) { mc = c; mi = i; }
    }
    // wave top-10 iou via 10 rounds of head-argmax butterfly
    #pragma unroll
    for (int r = 0; r < TK; r++) {
      float v = vio[0];
      #pragma unroll
      for (int o = 1; o < 64; o <<= 1) v = fmaxf(v, __shfl_xor(v, o));
      bool win = (vio[0] == v);
      unsigned long long wm = __ballot(win);
      int wl = (int)__builtin_ctzll(wm);
      if (lane == wl) {
        #pragma unroll
        for (int k = 0; k < TK-1; k++) vio[k]=vio[k+1];
        vio[TK-1] = -1.0f;
      }
      if (lane == r) mv = v;
    }
    if (lane < TK) { sh_c[wv][lane]=mc; sh_i[wv][lane]=mi; sh_v[wv][lane]=mv; }
    __syncthreads();

    // unified serial 4-way merge: lane0 = (cost,id) asc-lex, lane1 = (-iou,0) asc
    if (tid < 2) {
      bool isC = (tid == 0);
      int p0=0,p1=0,p2=0,p3=0;
      size_t slot = ((size_t)bg*2 + sp)*TK;
      for (int k = 0; k < TK; k++) {
        float k0 = isC ? sh_c[0][p0] : -sh_v[0][p0]; int j0 = isC ? sh_i[0][p0] : 0;
        float k1 = isC ? sh_c[1][p1] : -sh_v[1][p1]; int j1 = isC ? sh_i[1][p1] : 0;
        float k2 = isC ? sh_c[2][p2] : -sh_v[2][p2]; int j2 = isC ? sh_i[2][p2] : 0;
        float k3 = isC ? sh_c[3][p3] : -sh_v[3][p3]; int j3 = isC ? sh_i[3][p3] : 0;
        int sel = 0; float kv = k0; int jv = j0;
        if (k1 < kv || (k1 == kv && j1 < jv)) { kv=k1; jv=j1; sel=1; }
        if (k2 < kv || (k2 == kv && j2 < jv)) { kv=k2; jv=j2; sel=2; }
        if (k3 < kv || (k3 == kv && j3 < jv)) { kv=k3; jv=j3; sel=3; }
        if (sel==0) p0++; else if (sel==1) p1++; else if (sel==2) p2++; else p3++;
        if (isC) { part_c[slot+k]=kv; part_i[slot+k]=jv; } else { part_v[slot+k]=-kv; }
      }
    }
  }

  // last-block fold-in of the per-(b,g) final merge
  if (tid == 0) {
    __threadfence();
    int old = atomicAdd(done, 1);
    s_last = (old == (int)gridDim.x - 1) ? 1 : 0;
  }
  __syncthreads();
  if (s_last) {
    __threadfence();
    for (int t = tid; t < BB*GG; t += 256) {
      const float* g2 = grec + (size_t)t*GREC;
      if (g2[9] == 0.0f) continue;
      int b2 = t / GG, g = t - b2*GG;
      const float* pc = part_c + (size_t)t*2*TK;
      const int*   pi = part_i + (size_t)t*2*TK;
      const float* pv = part_v + (size_t)t*2*TK;
      // dyn_k: descending 2-way merge of iou lists, clamped at 0 (implicit zeros)
      int q0=0,q1=0; float vs=0.0f;
      for (int k = 0; k < TK; k++) {
        float b0 = pv[q0], b1 = pv[TK+q1];
        if (b0 >= b1) { vs += fmaxf(b0,0.0f); q0++; }
        else          { vs += fmaxf(b1,0.0f); q1++; }
      }
      int dynk = (int)vs; dynk = dynk < 1 ? 1 : (dynk > TK ? TK : dynk);
      int* mcb = mcount + (size_t)b2*AA;
      int* mgb = mgsum  + (size_t)b2*AA;
      int p0=0,p1=0;
      for (int k = 0; k < dynk; k++) {
        float c0 = pc[p0]; int i0 = pi[p0];
        float c1 = pc[TK+p1]; int i1 = pi[TK+p1];
        bool t0 = (c0 < c1) || (c0 == c1 && i0 < i1);
        int bi = t0 ? i0 : i1;
        if (t0) p0++; else p1++;
        atomicAdd(&mcb[bi], 1);
        atomicAdd(&mgb[bi], g);
      }
    }
  }
}

// per-anchor conflict resolution + loss contributions (+ fused finalize)
__global__ __launch_bounds__(256) void k_losses(const float* __restrict__ o8, const float* __restrict__ o16,
                                                const float* __restrict__ o32,
                                                const float* __restrict__ rec8, const float* __restrict__ grec,
                                                const unsigned char* __restrict__ cand,
                                                const int* __restrict__ mcount, const int* __restrict__ mgsum,
                                                const float* __restrict__ Dp, float* acc,
                                                int* done2, float* __restrict__ out) {
  int t = blockIdx.x * 256 + threadIdx.x;
  int b = t / AA, a = t - b*AA;
  int tid = threadIdx.x;

  const float* pb; int cs;
  if (a < 16384)      { pb = o8  + ((size_t)b*21)*16384 + a;           cs = 16384; }
  else if (a < 20480) { pb = o16 + ((size_t)b*21)*4096 + (a-16384);    cs = 4096;  }
  else                { pb = o32 + ((size_t)b*21)*1024 + (a-20480);    cs = 1024;  }

  int cnt = mcount[t];
  float fg = (cnt > 0) ? 1.0f : 0.0f;
  float obj = pb[(size_t)5*cs];
  float eo = fexp2_(-fabsf(obj) * RLN2F);
  float lobj = fmaxf(obj, 0.0f) - obj*fg + flog_(1.0f + eo);
  float liou = 0.0f, lcls = 0.0f;

  if (cnt > 0) {
    const float4* r4 = (const float4*)(rec8 + (size_t)t * 8);
    float4 v0 = r4[0], v1 = r4[1];
    int gstar;
    if (cnt == 1) {
      gstar = mgsum[t];
    } else {
      float xc, yc, rad; ageom(a, xc, yc, rad);
      int cd = cand[t];
      float best = 3.4e38f; gstar = 0;
      for (int g = 0; g < GG; g++) {
        const float* gg = grec + (size_t)(b*GG + g) * GREC;
        float valid = gg[9];
        float iou = prob_iou_fast(gg[0],gg[1],gg[2],gg[3],gg[4],gg[5],
                                  v0.x,v0.y,v0.z,v0.w,v1.x,v1.y);
        if (valid == 0.0f) iou = 0.0f;
        int gcls = __float_as_int(gg[8]);
        float cost = (v1.z + Dp[((size_t)b*NCLS + gcls)*AA + a]) + 3.0f * (-flog_(iou + 1e-8f));
        float dx = fabsf(xc - gg[0]), dy = fabsf(yc - gg[1]);
        bool vb = (valid != 0.0f);
        bool ib = (dx < 0.5f*gg[6]) && (dy < 0.5f*gg[7]) && vb;
        bool ic = (dx < rad) && (dy < rad) && vb;
        if (!(ib && ic)) cost += 1e5f;
        if (!cd)         cost += 1e6f;
        if (!vb)         cost += 1e9f;
        if (cost < best) { best = cost; gstar = g; }
      }
    }
    const float* gg = grec + (size_t)(b*GG + gstar) * GREC;
    float I = prob_iou_fast(gg[0],gg[1],gg[2],gg[3],gg[4],gg[5],
                            v0.x,v0.y,v0.z,v0.w,v1.x,v1.y);
    if (gg[9] == 0.0f) I = 0.0f;
    liou = 1.0f - I;
    int gcls = __float_as_int(gg[8]);
    #pragma unroll
    for (int c = 0; c < NCLS; c++) {
      float xl = pb[(size_t)(6+c)*cs];
      float tgt = (c == gcls) ? I : 0.0f;
      float ex = fexp2_(-fabsf(xl) * RLN2F);
      lcls += fmaxf(xl, 0.0f) - xl*tgt + flog_(1.0f + ex);
    }
  }

  // fused 4-value block reduction (single barrier)
  float s0 = fg, s1 = liou, s2 = lobj, s3 = lcls;
  #pragma unroll
  for (int o = 32; o > 0; o >>= 1) {
    s0 += __shfl_down(s0, o); s1 += __shfl_down(s1, o);
    s2 += __shfl_down(s2, o); s3 += __shfl_down(s3, o);
  }
  __shared__ float sw[4][4];
  __shared__ int s_last;
  int wid = tid >> 6, lane = tid & 63;
  if (lane == 0) { sw[wid][0]=s0; sw[wid][1]=s1; sw[wid][2]=s2; sw[wid][3]=s3; }
  __syncthreads();
  if (tid == 0) {
    atomicAdd(&acc[0], sw[0][0]+sw[1][0]+sw[2][0]+sw[3][0]);
    atomicAdd(&acc[1], sw[0][1]+sw[1][1]+sw[2][1]+sw[3][1]);
    atomicAdd(&acc[2], sw[0][2]+sw[1][2]+sw[2][2]+sw[3][2]);
    atomicAdd(&acc[3], sw[0][3]+sw[1][3]+sw[2][3]+sw[3][3]);
    __threadfence();
    int old = atomicAdd(done2, 1);
    s_last = (old == (int)gridDim.x - 1) ? 1 : 0;
  }
  __syncthreads();
  if (s_last && tid == 0) {
    __threadfence();
    float nfg = atomicAdd(&acc[0], 0.0f);
    float a1  = atomicAdd(&acc[1], 0.0f);
    float a2  = atomicAdd(&acc[2], 0.0f);
    float a3  = atomicAdd(&acc[3], 0.0f);
    float ng  = atomicAdd(&acc[4], 0.0f);
    float nf = fmaxf(nfg, 1.0f);
    float li = a1 / nf, lo = a2 / nf, lc = a3 / nf;
    float l5 = 5.0f * li;
    out[0] = l5 + lo + lc;
    out[1] = l5;
    out[2] = lo;
    out[3] = lc;
    out[4] = 0.0f;
    out[5] = nfg / fmaxf(ng, 1.0f);
  }
}

// ---------- launch ----------

extern "C" void kernel_launch(void* const* d_in, const int* in_sizes, int n_in,
                              void* d_out, int out_size, void* d_ws, size_t ws_size,
                              hipStream_t stream) {
  const float* o8     = (const float*)d_in[0];
  const float* o16    = (const float*)d_in[1];
  const float* o32    = (const float*)d_in[2];
  const float* labels = (const float*)d_in[3];
  float* out = (float*)d_out;

  char* w = (char*)d_ws;
  float* rec8 = (float*)w; w += (size_t)BB*AA*8*sizeof(float);
  float* Dp   = (float*)w; w += (size_t)BB*NCLS*AA*sizeof(float);
  int* clist  = (int*)w;   w += (size_t)BB*AA*sizeof(int);
  float* grec = (float*)w; w += (size_t)BB*GG*GREC*sizeof(float);
  float* part_c = (float*)w; w += (size_t)BB*GG*2*TK*sizeof(float);
  int*   part_i = (int*)w;   w += (size_t)BB*GG*2*TK*sizeof(int);
  float* part_v = (float*)w; w += (size_t)BB*GG*2*TK*sizeof(float);
  // zeroed region (contiguous): cand, mcount, mgsum, ncand, done, acc
  unsigned char* cand = (unsigned char*)w; w += (size_t)BB*AA;
  int* mcount = (int*)w;   w += (size_t)BB*AA*sizeof(int);
  int* mgsum  = (int*)w;   w += (size_t)BB*AA*sizeof(int);
  int* ncand  = (int*)w;   w += 128;
  int* done   = (int*)w;   w += 128;
  float* acc  = (float*)w; w += 256;
  size_t zbytes = (size_t)((char*)w - (char*)cand);

  hipMemsetAsync(cand, 0, zbytes, stream);

  int nBA = BB*AA;  // 172032 = 672*256
  k_gtraster<<<BB*GG, 256, 0, stream>>>(labels, grec, acc, cand);
  k_decode<<<nBA/256, 256, 0, stream>>>(o8, o16, o32, rec8, Dp, cand, ncand, clist);
  k_assign<<<BB*GG*2, 256, 0, stream>>>(rec8, grec, Dp, ncand, clist, part_c, part_i, part_v,
                                        done, mcount, mgsum);
  k_losses<<<nBA/256, 256, 0, stream>>>(o8, o16, o32, rec8, grec, cand, mcount, mgsum, Dp, acc,
                                        done + 1, out);
}

// Round 9
// 240.973 us; speedup vs baseline: 1.0917x; 1.0917x over previous
//
#include <hip/hip_runtime.h>
#include <math.h>

#define NCLS 15
constexpr int BB = 8;
constexpr int GG = 60;
constexpr int AA = 21504;   // 128*128 + 64*64 + 32*32
constexpr int TK = 10;
constexpr int GREC = 12;
constexpr int LSTR = 11;    // padded LDS list stride (odd -> <=2-way banks, free)

// ---------- fast math (hw-native, ~1ulp) ----------
__device__ __forceinline__ float frcp_(float x){ return __builtin_amdgcn_rcpf(x); }
__device__ __forceinline__ float flog2_(float x){ return __builtin_amdgcn_logf(x); }
__device__ __forceinline__ float fexp2_(float x){ return __builtin_amdgcn_exp2f(x); }
__device__ __forceinline__ float fsqrt_(float x){ return __builtin_amdgcn_sqrtf(x); }
#define LN2F  0.69314718055994531f
#define RLN2F 1.44269504088896341f
#define R2PIF 0.15915494309189535f
__device__ __forceinline__ float flog_(float x){ return flog2_(x) * LN2F; }
__device__ __forceinline__ float fexp_(float x){ return fexp2_(x * RLN2F); }
__device__ __forceinline__ float fsig_(float x){ return frcp_(1.0f + fexp2_(-x * RLN2F)); }

// ---------- helpers ----------

__device__ __forceinline__ void ageom(int a, float& xc, float& yc, float& rad) {
  if (a < 16384) {
    int i = a >> 7, j = a & 127;
    xc = (j + 0.5f) * 8.0f;  yc = (i + 0.5f) * 8.0f;  rad = 20.0f;
  } else if (a < 20480) {
    int l = a - 16384; int i = l >> 6, j = l & 63;
    xc = (j + 0.5f) * 16.0f; yc = (i + 0.5f) * 16.0f; rad = 40.0f;
  } else {
    int l = a - 20480; int i = l >> 5, j = l & 31;
    xc = (j + 0.5f) * 32.0f; yc = (i + 0.5f) * 32.0f; rad = 80.0f;
  }
}

__device__ __forceinline__ float prob_iou_fast(float x1,float y1,float a1,float b1,float c1,float d1,
                                               float x2,float y2,float a2,float b2,float c2,float d2) {
  float dx = x1 - x2, dy = y1 - y2;
  float Av = a1 + a2, Bv = b1 + b2, Cv = c1 + c2;
  float den = Av*Bv - Cv*Cv + 1e-8f;
  float q = 0.25f*(Av*dy*dy + Bv*dx*dx) - 0.5f*(Cv*dx*dy);
  float t12 = q * frcp_(den);
  float t3 = 0.5f*LN2F*(flog2_(den) - flog2_(4.0f*fsqrt_(d1*d2) + 1e-8f));
  float bd = t12 + t3;
  bd = fminf(fmaxf(bd, 1e-8f), 100.0f);
  float e = 1.0f - fexp2_(-bd * RLN2F);
  e = fminf(fmaxf(e, 0.0f), 1.0f);
  return 1.0f - fsqrt_(e);
}

// identical op sequence used by decode and fg-recompute
__device__ __forceinline__ void decode_anchor(const float* pb, int cs, int i, int j, float s,
                                              float& x, float& y, float& cA, float& cB,
                                              float& cC, float& cD, float& S, float (&xls)[NCLS]) {
  float tx  = pb[0];
  float ty  = pb[(size_t)cs];
  float tw  = pb[(size_t)2*cs];
  float th  = pb[(size_t)3*cs];
  float ang = pb[(size_t)4*cs];
  float obj = pb[(size_t)5*cs];
  x = (tx + (float)j) * s;
  y = (ty + (float)i) * s;
  float w = fexp_(tw) * s;
  float h = fexp_(th) * s;
  float w2 = w*w / 12.0f, h2 = h*h / 12.0f;
  float rev = ang * R2PIF;
  float cc = __builtin_amdgcn_cosf(rev), sn = __builtin_amdgcn_sinf(rev);
  cA = w2*cc*cc + h2*sn*sn;
  cB = w2*sn*sn + h2*cc*cc;
  cC = (w2 - h2)*cc*sn;
  cD = fmaxf(cA*cB - cC*cC, 0.0f);
  float sobj = fsig_(obj);
  S = 0.0f;
  #pragma unroll
  for (int c = 0; c < NCLS; c++) {
    float xl = pb[(size_t)(6+c)*cs];
    xls[c] = xl;
    float p = fsqrt_(fsig_(xl) * sobj);
    p = fminf(fmaxf(p, 1e-7f), 1.0f - 1e-7f);
    S -= flog_(1.0f - p);
  }
}

__device__ __forceinline__ void ins_cost(float (&cst)[TK], int (&cid)[TK], float c, int id) {
  bool ins = (c < cst[TK-1]) || (c == cst[TK-1] && id < cid[TK-1]);
  if (ins) {
    cst[TK-1] = c; cid[TK-1] = id;
    #pragma unroll
    for (int k = TK-1; k > 0; k--) {
      float tc = cst[k-1]; int ti = cid[k-1];
      bool sw = (cst[k] < tc) || (cst[k] == tc && cid[k] < ti);
      if (sw) { cst[k-1] = cst[k]; cid[k-1] = cid[k]; cst[k] = tc; cid[k] = ti; }
    }
  }
}

__device__ __forceinline__ void ins_vio(float (&vio)[TK], float v) {
  if (v > vio[TK-1]) {
    vio[TK-1] = v;
    #pragma unroll
    for (int k = TK-1; k > 0; k--) {
      float tv = vio[k-1];
      bool sw = vio[k] > tv;
      if (sw) { vio[k-1] = vio[k]; vio[k] = tv; }
    }
  }
}

// ---------- kernels ----------

// one block per (b,g): gt record + cand raster (bit-identical per-cell predicate)
__global__ __launch_bounds__(256) void k_raster(const float* __restrict__ labels,
                                                float* __restrict__ grec, float* acc,
                                                unsigned char* __restrict__ cand) {
  int bg = blockIdx.x;
  int b = bg / GG;
  __shared__ float s_f[4];
  __shared__ int s_v;
  if (threadIdx.x == 0) {
    const float* L = labels + (size_t)bg*6;
    float ssum = 0.0f;
    for (int k = 0; k < 6; k++) ssum += L[k];
    float valid = (ssum > 0.0f) ? 1.0f : 0.0f;
    float x=L[1], y=L[2], w=L[3], h=L[4], ang=L[5];
    float w2=w*w/12.0f, h2=h*h/12.0f;
    float cc=cosf(ang), sn=sinf(ang);
    float cA=w2*cc*cc+h2*sn*sn, cB=w2*sn*sn+h2*cc*cc, cC=(w2-h2)*cc*sn;
    float cD=fmaxf(cA*cB-cC*cC, 0.0f);
    float* gr = grec + (size_t)bg*GREC;
    gr[0]=x; gr[1]=y; gr[2]=cA; gr[3]=cB; gr[4]=cC; gr[5]=cD;
    gr[6]=w; gr[7]=h; gr[8]=__int_as_float((int)L[0]); gr[9]=valid; gr[10]=0; gr[11]=0;
    if (valid != 0.0f) atomicAdd(&acc[4], 1.0f);
    s_f[0]=x; s_f[1]=y; s_f[2]=0.5f*w; s_f[3]=0.5f*h;
    s_v = (valid != 0.0f) ? 1 : 0;
  }
  __syncthreads();
  if (!s_v) return;
  float gx=s_f[0], gy=s_f[1], hw=s_f[2], hh=s_f[3];
  unsigned char* cb = cand + (size_t)b*AA;
  #pragma unroll
  for (int lvl = 0; lvl < 3; lvl++) {
    const int   W    = (lvl==0)?128:((lvl==1)?64:32);
    const int   base = (lvl==0)?0:((lvl==1)?16384:20480);
    const float s    = (lvl==0)?8.0f:((lvl==1)?16.0f:32.0f);
    const float invs = (lvl==0)?0.125f:((lvl==1)?0.0625f:0.03125f);
    const float rad  = 2.5f*s;
    #pragma unroll
    for (int rc = 0; rc < 2; rc++) {
      float mx = rc ? rad : hw;
      float my = rc ? rad : hh;
      int jlo = (int)floorf((gx - mx)*invs - 0.5f) - 1; if (jlo < 0) jlo = 0;
      int jhi = (int)ceilf ((gx + mx)*invs - 0.5f) + 1; if (jhi > W-1) jhi = W-1;
      int ilo = (int)floorf((gy - my)*invs - 0.5f) - 1; if (ilo < 0) ilo = 0;
      int ihi = (int)ceilf ((gy + my)*invs - 0.5f) + 1; if (ihi > W-1) ihi = W-1;
      if (jhi < jlo || ihi < ilo) continue;
      int nw = jhi - jlo + 1;
      int tot = nw * (ihi - ilo + 1);
      for (int k = threadIdx.x; k < tot; k += 256) {
        int q = k / nw;
        int ii = ilo + q;
        int jj = jlo + (k - q*nw);
        float dx = fabsf(((float)jj + 0.5f)*s - gx);
        float dy = fabsf(((float)ii + 0.5f)*s - gy);
        if (dx < mx && dy < my) cb[base + ii*W + jj] = 1;
      }
    }
  }
}

// decode ONLY cand anchors -> compacted crec (32B rec: x,y,cA,cB,cC,cD,aid,S) + Dp planes
__global__ __launch_bounds__(256) void k_decode(const float* __restrict__ o8, const float* __restrict__ o16,
                                                const float* __restrict__ o32,
                                                const unsigned char* __restrict__ cand,
                                                float* __restrict__ crec, float* __restrict__ Dp,
                                                int* ncand) {
  int t = blockIdx.x*256 + threadIdx.x;
  int b = t / AA, a = t - b*AA;
  int pred = cand[t];
  unsigned long long m = __ballot(pred != 0);
  if (!m) return;
  int lane = threadIdx.x & 63;
  int bpos = 0;
  if (lane == 0) bpos = atomicAdd(&ncand[b], (int)__popcll(m));
  bpos = __shfl(bpos, 0);
  if (!pred) return;
  int pos = bpos + (int)__popcll(m & ((1ull << lane) - 1ull));
  const float* pb; int cs, i, j; float s;
  if (a < 16384)      { pb = o8  + ((size_t)b*21)*16384 + a;           cs = 16384; i = a>>7; j = a&127; s = 8.0f; }
  else if (a < 20480) { int l = a-16384; pb = o16 + ((size_t)b*21)*4096 + l; cs = 4096; i = l>>6; j = l&63; s = 16.0f; }
  else                { int l = a-20480; pb = o32 + ((size_t)b*21)*1024 + l; cs = 1024; i = l>>5; j = l&31; s = 32.0f; }
  float x,y,cA,cB,cC,cD,S; float xls[NCLS];
  decode_anchor(pb, cs, i, j, s, x,y,cA,cB,cC,cD,S, xls);
  float sobj = fsig_(pb[(size_t)5*cs]);
  float* dpb = Dp + (size_t)b*NCLS*AA + a;
  #pragma unroll
  for (int c = 0; c < NCLS; c++) {
    float p = fsqrt_(fsig_(xls[c]) * sobj);
    p = fminf(fmaxf(p, 1e-7f), 1.0f - 1e-7f);
    dpb[(size_t)c*AA] = flog_(1.0f - p) - flog_(p);
  }
  float4* dst = (float4*)(crec + ((size_t)b*AA + pos)*8);
  dst[0] = make_float4(x, y, cA, cB);
  dst[1] = make_float4(cC, cD, __int_as_float(a), S);
}

// 2 blocks per (b,g): sequential scan of compacted stream -> per-thread top-10s
// -> stride-11 LDS tree merge -> part lists. Last block: 2-way merge + dyn_k + atomics.
__global__ __launch_bounds__(256) void k_assign(const float* __restrict__ crec, const float* __restrict__ grec,
                                                const float* __restrict__ Dp, const int* __restrict__ ncand,
                                                float* __restrict__ part_c, int* __restrict__ part_i,
                                                float* __restrict__ part_v,
                                                int* done, int* __restrict__ mcount, int* __restrict__ mgsum) {
  int blk = blockIdx.x;
  int bg = blk >> 1, sp = blk & 1;
  int b = bg / GG;
  int tid = threadIdx.x;
  const float* gr = grec + (size_t)bg*GREC;

  __shared__ float sh_c[256*LSTR];
  __shared__ int   sh_i[256*LSTR];
  __shared__ float sh_v[256*LSTR];
  __shared__ int s_nboth, s_last;

  if (gr[9] != 0.0f) {
    if (tid == 0) s_nboth = 0;
    __syncthreads();
    float gx=gr[0], gy=gr[1], gA=gr[2], gB=gr[3], gC=gr[4], gD=gr[5];
    float hw=0.5f*gr[6], hh=0.5f*gr[7];
    int gcls = __float_as_int(gr[8]);
    const float* dpp = Dp + ((size_t)b*NCLS + gcls)*AA;
    const float4* cr = (const float4*)(crec + (size_t)b*AA*8);
    int n = ncand[b];

    float cst[TK]; int cid[TK]; float vio[TK];
    #pragma unroll
    for (int k = 0; k < TK; k++) { cst[k]=3.4e38f; cid[k]=0x7fffffff; vio[k]=-1.0f; }

    for (int k = sp*256 + tid; k < n; k += 512) {
      float4 c0 = cr[2*k], c1 = cr[2*k+1];
      float iou = prob_iou_fast(gx,gy,gA,gB,gC,gD, c0.x,c0.y,c0.z,c0.w,c1.x,c1.y);
      if (iou > vio[TK-1]) ins_vio(vio, iou);
      int a = __float_as_int(c1.z);
      float xc, yc, rad; ageom(a, xc, yc, rad);
      float dx = fabsf(xc-gx), dy = fabsf(yc-gy);
      bool both = (dx<hw) && (dy<hh) && (dx<rad) && (dy<rad);
      if (both || *((volatile int*)&s_nboth) < TK) {  // sound prune: both-cost<425 << 1e5
        float cost = (c1.w + dpp[a]) + 3.0f*(-flog_(iou + 1e-8f));
        if (!both) cost += 1e5f;
        ins_cost(cst, cid, cost, a);
        if (both) atomicAdd(&s_nboth, 1);
      }
    }

    int base = tid*LSTR;
    #pragma unroll
    for (int k = 0; k < TK; k++) { sh_c[base+k]=cst[k]; sh_i[base+k]=cid[k]; sh_v[base+k]=vio[k]; }
    __syncthreads();
    for (int step = 128; step >= 1; step >>= 1) {
      if (tid < step) {
        int A = tid*LSTR, B2 = (tid+step)*LSTR;
        float oc[TK]; int oi[TK]; float ov[TK];
        int pi=0, pj=0;
        #pragma unroll
        for (int k = 0; k < TK; k++) {
          float ca = sh_c[A+pi]; int ia = sh_i[A+pi];
          float cb = sh_c[B2+pj]; int ib = sh_i[B2+pj];
          bool ta = (ca < cb) || (ca == cb && ia < ib);
          oc[k] = ta ? ca : cb; oi[k] = ta ? ia : ib;
          pi += ta ? 1 : 0; pj += ta ? 0 : 1;
        }
        int qi=0, qj=0;
        #pragma unroll
        for (int k = 0; k < TK; k++) {
          float va = sh_v[A+qi], vb2 = sh_v[B2+qj];
          bool ta = (va >= vb2);
          ov[k] = ta ? va : vb2;
          qi += ta ? 1 : 0; qj += ta ? 0 : 1;
        }
        #pragma unroll
        for (int k = 0; k < TK; k++) { sh_c[A+k]=oc[k]; sh_i[A+k]=oi[k]; sh_v[A+k]=ov[k]; }
      }
      __syncthreads();
    }
    if (tid == 0) {
      size_t slot = ((size_t)bg*2 + sp)*TK;
      #pragma unroll
      for (int k = 0; k < TK; k++) { part_c[slot+k]=sh_c[k]; part_i[slot+k]=sh_i[k]; part_v[slot+k]=sh_v[k]; }
    }
  }

  // last-block fold-in of the per-(b,g) final merge
  if (tid == 0) {
    __threadfence();
    int old = atomicAdd(done, 1);
    s_last = (old == (int)gridDim.x - 1) ? 1 : 0;
  }
  __syncthreads();
  if (s_last) {
    __threadfence();
    for (int t4 = tid; t4 < BB*GG; t4 += 256) {
      const float* g2 = grec + (size_t)t4*GREC;
      if (g2[9] == 0.0f) continue;
      int b2 = t4 / GG, g = t4 - b2*GG;
      const float* pc = part_c + (size_t)t4*2*TK;
      const int*   pi = part_i + (size_t)t4*2*TK;
      const float* pv = part_v + (size_t)t4*2*TK;
      int q0=0, q1=0; float vs = 0.0f;
      for (int k = 0; k < TK; k++) {
        float b0 = pv[q0], b1 = pv[TK+q1];
        if (b0 >= b1) { vs += fmaxf(b0, 0.0f); q0++; }
        else          { vs += fmaxf(b1, 0.0f); q1++; }
      }
      int dynk = (int)vs; dynk = dynk < 1 ? 1 : (dynk > TK ? TK : dynk);
      int* mcb = mcount + (size_t)b2*AA;
      int* mgb = mgsum  + (size_t)b2*AA;
      int p0=0, p1=0;
      for (int k = 0; k < dynk; k++) {
        float c0 = pc[p0]; int i0 = pi[p0];
        float c1 = pc[TK+p1]; int i1 = pi[TK+p1];
        bool t0 = (c0 < c1) || (c0 == c1 && i0 < i1);
        int bi = t0 ? i0 : i1;
        if (t0) p0++; else p1++;
        atomicAdd(&mcb[bi], 1);
        atomicAdd(&mgb[bi], g);
      }
    }
  }
}

// per-anchor losses; fg anchors recompute their record bit-identically; last block finalizes
__global__ __launch_bounds__(256) void k_losses(const float* __restrict__ o8, const float* __restrict__ o16,
                                                const float* __restrict__ o32,
                                                const float* __restrict__ grec,
                                                const unsigned char* __restrict__ cand,
                                                const int* __restrict__ mcount, const int* __restrict__ mgsum,
                                                const float* __restrict__ Dp, float* acc,
                                                int* done2, float* __restrict__ out) {
  int t = blockIdx.x*256 + threadIdx.x;
  int b = t / AA, a = t - b*AA;
  int tid = threadIdx.x;

  const float* pb; int cs, i, j; float s;
  if (a < 16384)      { pb = o8  + ((size_t)b*21)*16384 + a;           cs = 16384; i = a>>7; j = a&127; s = 8.0f; }
  else if (a < 20480) { int l = a-16384; pb = o16 + ((size_t)b*21)*4096 + l; cs = 4096; i = l>>6; j = l&63; s = 16.0f; }
  else                { int l = a-20480; pb = o32 + ((size_t)b*21)*1024 + l; cs = 1024; i = l>>5; j = l&31; s = 32.0f; }

  int cnt = mcount[t];
  float fg = (cnt > 0) ? 1.0f : 0.0f;
  float obj = pb[(size_t)5*cs];
  float lobj = fmaxf(obj, 0.0f) - obj*fg + flog_(1.0f + fexp2_(-fabsf(obj)*RLN2F));
  float liou = 0.0f, lcls = 0.0f;

  if (cnt > 0) {
    float x,y,cA,cB,cC,cD,S; float xls[NCLS];
    decode_anchor(pb, cs, i, j, s, x,y,cA,cB,cC,cD,S, xls);
    int gstar;
    if (cnt == 1) {
      gstar = mgsum[t];
    } else {
      float xc, yc, rad; ageom(a, xc, yc, rad);
      int cd = cand[t];
      float best = 3.4e38f; gstar = 0;
      for (int g = 0; g < GG; g++) {
        const float* gg = grec + (size_t)(b*GG + g)*GREC;
        float valid = gg[9];
        float iou = prob_iou_fast(gg[0],gg[1],gg[2],gg[3],gg[4],gg[5], x,y,cA,cB,cC,cD);
        if (valid == 0.0f) iou = 0.0f;
        int gcls = __float_as_int(gg[8]);
        float cost = (S + Dp[((size_t)b*NCLS + gcls)*AA + a]) + 3.0f*(-flog_(iou + 1e-8f));
        float dx = fabsf(xc - gg[0]), dy = fabsf(yc - gg[1]);
        bool vb2 = (valid != 0.0f);
        bool ib = (dx < 0.5f*gg[6]) && (dy < 0.5f*gg[7]) && vb2;
        bool ic = (dx < rad) && (dy < rad) && vb2;
        if (!(ib && ic)) cost += 1e5f;
        if (!cd)         cost += 1e6f;
        if (!vb2)        cost += 1e9f;
        if (cost < best) { best = cost; gstar = g; }
      }
    }
    const float* gg = grec + (size_t)(b*GG + gstar)*GREC;
    float I = prob_iou_fast(gg[0],gg[1],gg[2],gg[3],gg[4],gg[5], x,y,cA,cB,cC,cD);
    if (gg[9] == 0.0f) I = 0.0f;
    liou = 1.0f - I;
    int gcls = __float_as_int(gg[8]);
    #pragma unroll
    for (int c = 0; c < NCLS; c++) {
      float xl = xls[c];
      float tgt = (c == gcls) ? I : 0.0f;
      lcls += fmaxf(xl, 0.0f) - xl*tgt + flog_(1.0f + fexp2_(-fabsf(xl)*RLN2F));
    }
  }

  float s0 = fg, s1 = liou, s2 = lobj, s3 = lcls;
  #pragma unroll
  for (int o = 32; o > 0; o >>= 1) {
    s0 += __shfl_down(s0, o); s1 += __shfl_down(s1, o);
    s2 += __shfl_down(s2, o); s3 += __shfl_down(s3, o);
  }
  __shared__ float sw[4][4];
  __shared__ int s_last;
  int wid = tid >> 6, lane = tid & 63;
  if (lane == 0) { sw[wid][0]=s0; sw[wid][1]=s1; sw[wid][2]=s2; sw[wid][3]=s3; }
  __syncthreads();
  if (tid == 0) {
    atomicAdd(&acc[0], sw[0][0]+sw[1][0]+sw[2][0]+sw[3][0]);
    atomicAdd(&acc[1], sw[0][1]+sw[1][1]+sw[2][1]+sw[3][1]);
    atomicAdd(&acc[2], sw[0][2]+sw[1][2]+sw[2][2]+sw[3][2]);
    atomicAdd(&acc[3], sw[0][3]+sw[1][3]+sw[2][3]+sw[3][3]);
    __threadfence();
    int old = atomicAdd(done2, 1);
    s_last = (old == (int)gridDim.x - 1) ? 1 : 0;
  }
  __syncthreads();
  if (s_last && tid == 0) {
    __threadfence();
    float nfg = atomicAdd(&acc[0], 0.0f);
    float a1  = atomicAdd(&acc[1], 0.0f);
    float a2  = atomicAdd(&acc[2], 0.0f);
    float a3  = atomicAdd(&acc[3], 0.0f);
    float ng  = atomicAdd(&acc[4], 0.0f);
    float nf = fmaxf(nfg, 1.0f);
    float li = a1 / nf, lo = a2 / nf, lc = a3 / nf;
    float l5 = 5.0f * li;
    out[0] = l5 + lo + lc;
    out[1] = l5;
    out[2] = lo;
    out[3] = lc;
    out[4] = 0.0f;
    out[5] = nfg / fmaxf(ng, 1.0f);
  }
}

// ---------- launch ----------

extern "C" void kernel_launch(void* const* d_in, const int* in_sizes, int n_in,
                              void* d_out, int out_size, void* d_ws, size_t ws_size,
                              hipStream_t stream) {
  const float* o8     = (const float*)d_in[0];
  const float* o16    = (const float*)d_in[1];
  const float* o32    = (const float*)d_in[2];
  const float* labels = (const float*)d_in[3];
  float* out = (float*)d_out;

  char* w = (char*)d_ws;
  float* crec = (float*)w; w += (size_t)BB*AA*8*sizeof(float);
  float* Dp   = (float*)w; w += (size_t)BB*NCLS*AA*sizeof(float);
  float* grec = (float*)w; w += (size_t)BB*GG*GREC*sizeof(float);
  float* part_c = (float*)w; w += (size_t)BB*GG*2*TK*sizeof(float);
  int*   part_i = (int*)w;   w += (size_t)BB*GG*2*TK*sizeof(int);
  float* part_v = (float*)w; w += (size_t)BB*GG*2*TK*sizeof(float);
  // contiguous zero region: cand, mcount, mgsum, ncand, done, acc
  unsigned char* cand = (unsigned char*)w; w += (size_t)BB*AA;
  int* mcount = (int*)w;   w += (size_t)BB*AA*sizeof(int);
  int* mgsum  = (int*)w;   w += (size_t)BB*AA*sizeof(int);
  int* ncand  = (int*)w;   w += 128;
  int* done   = (int*)w;   w += 128;
  float* acc  = (float*)w; w += 256;
  size_t zbytes = (size_t)((char*)w - (char*)cand);

  hipMemsetAsync(cand, 0, zbytes, stream);

  int nBA = BB*AA;  // 172032 = 672*256
  k_raster<<<BB*GG, 256, 0, stream>>>(labels, grec, acc, cand);
  k_decode<<<nBA/256, 256, 0, stream>>>(o8, o16, o32, cand, crec, Dp, ncand);
  k_assign<<<BB*GG*2, 256, 0, stream>>>(crec, grec, Dp, ncand, part_c, part_i, part_v,
                                        done, mcount, mgsum);
  k_losses<<<nBA/256, 256, 0, stream>>>(o8, o16, o32, grec, cand, mcount, mgsum, Dp, acc,
                                        done + 1, out);
}